// Round 2
// baseline (367.435 us; speedup 1.0000x reference)
//
#include <hip/hip_runtime.h>
#include <hip/hip_bf16.h>
#include <math.h>

#define N_NODESC 100000
#define N_EDGESC 1600000
#define IN_DIMC 256
#define HIDC 64
#define ALPHAC 0.1f
#define BIASC 1e-4f
#define EOSC 1e-10f

#define MC (N_EDGESC + N_NODESC)   // 1,700,000
#define W20SCALE 1048576.0f        // 2^20
#define W20INV (1.0f / 1048576.0f)
#define SUMMASK ((1ull << 40) - 1)
#define CNTONE (1ull << 40)
#define EPB 8                      // edges per thread in edge_kernel

typedef __attribute__((ext_vector_type(8))) short short8;
typedef __attribute__((ext_vector_type(4))) float f32x4;

#define WT_STRIDE 264  // bf16 per j-row: 256 + 8 pad (528 B, 16B-aligned)

// edges may arrive as int32 (JAX x64-off) or int64 little-endian.
__device__ inline void load_edge(const int* __restrict__ edges, int e, int is64,
                                 int& src, int& dst) {
    if (is64) {
        const int2 a = ((const int2*)edges)[e];
        const int2 b = ((const int2*)edges)[N_EDGESC + e];
        src = a.x; dst = b.x;
    } else {
        src = edges[e];
        dst = edges[N_EDGESC + e];
    }
}

__device__ inline short pkbf(float x) {
    union { __hip_bfloat16 b; short s; } u;
    u.b = __float2bfloat16(x);
    return u.s;
}

// ---------------------------------------------------------------------------
// node kernel (MFMA): q[n] = relu(feat[n] @ W + b) @ (We[:64]+We[64:])
// 2 node-tiles per wave. Block 0 detects int32/int64 edge layout.
// Also zeroes the 2*N u64 degree tables (one entry per thread grid-wide).
__global__ __launch_bounds__(256, 3) void node_kernel(
    const float* __restrict__ features,
    const float* __restrict__ W_emb,
    const float* __restrict__ b_emb,
    const float* __restrict__ W_edge,
    const int* __restrict__ edges,
    float* __restrict__ q,
    unsigned long long* __restrict__ deg,  // [2*N] u64, zeroed here
    int* __restrict__ flag) {
    __shared__ __align__(16) short Wt[HIDC * WT_STRIDE];  // ~33.8 KB
    const int tid = threadIdx.x;
    {
        const int gid = blockIdx.x * 256 + tid;
        if (gid < 2 * N_NODESC) deg[gid] = 0ull;
    }
    if (blockIdx.x == 0 && tid == 0) {
        int z = 0;
        #pragma unroll
        for (int i = 0; i < 16; ++i) z |= edges[2 * i + 1];
        *flag = (z == 0) ? 1 : 0;  // 1 => int64 layout
    }
    {
        const float4* Wg = (const float4*)W_emb;
        #pragma unroll
        for (int i = 0; i < 16; ++i) {
            const int f4 = tid + 256 * i;
            const float4 g = Wg[f4];
            const int flat = 4 * f4;
            const int k = flat >> 6;
            const int j0 = flat & 63;
            Wt[(j0 + 0) * WT_STRIDE + k] = pkbf(g.x);
            Wt[(j0 + 1) * WT_STRIDE + k] = pkbf(g.y);
            Wt[(j0 + 2) * WT_STRIDE + k] = pkbf(g.z);
            Wt[(j0 + 3) * WT_STRIDE + k] = pkbf(g.w);
        }
    }
    const int lane = tid & 63;
    const int wave = tid >> 6;
    const int quad = lane >> 4;
    const int m = lane & 15;
    f32x4 accA[4], accB[4];
    float wsum4[4];
    #pragma unroll
    for (int nt = 0; nt < 4; ++nt) {
        const int j = m + 16 * nt;
        const float b = b_emb[j];
        accA[nt] = (f32x4){b, b, b, b};
        accB[nt] = (f32x4){b, b, b, b};
        wsum4[nt] = W_edge[j] + W_edge[HIDC + j];
    }
    __syncthreads();

    const int node0A = blockIdx.x * 128 + wave * 16;
    const int node0B = node0A + 64;
    const float* frA = features + (size_t)min(node0A + m, N_NODESC - 1) * IN_DIMC;
    const float* frB = features + (size_t)min(node0B + m, N_NODESC - 1) * IN_DIMC;

    #pragma unroll
    for (int ks = 0; ks < 8; ++ks) {
        const int kk = ks * 32 + quad * 8;
        const float4 fa0 = *(const float4*)(frA + kk);
        const float4 fb0 = *(const float4*)(frA + kk + 4);
        const float4 fa1 = *(const float4*)(frB + kk);
        const float4 fb1 = *(const float4*)(frB + kk + 4);
        short8 afA, afB;
        afA[0] = pkbf(fa0.x); afA[1] = pkbf(fa0.y);
        afA[2] = pkbf(fa0.z); afA[3] = pkbf(fa0.w);
        afA[4] = pkbf(fb0.x); afA[5] = pkbf(fb0.y);
        afA[6] = pkbf(fb0.z); afA[7] = pkbf(fb0.w);
        afB[0] = pkbf(fa1.x); afB[1] = pkbf(fa1.y);
        afB[2] = pkbf(fa1.z); afB[3] = pkbf(fa1.w);
        afB[4] = pkbf(fb1.x); afB[5] = pkbf(fb1.y);
        afB[6] = pkbf(fb1.z); afB[7] = pkbf(fb1.w);
        #pragma unroll
        for (int nt = 0; nt < 4; ++nt) {
            const short8 bf =
                *(const short8*)&Wt[(m + 16 * nt) * WT_STRIDE + kk];
            accA[nt] = __builtin_amdgcn_mfma_f32_16x16x32_bf16(afA, bf, accA[nt],
                                                               0, 0, 0);
            accB[nt] = __builtin_amdgcn_mfma_f32_16x16x32_bf16(afB, bf, accB[nt],
                                                               0, 0, 0);
        }
    }

    #pragma unroll
    for (int r = 0; r < 4; ++r) {
        float sA = 0.f, sB = 0.f;
        #pragma unroll
        for (int nt = 0; nt < 4; ++nt) {
            sA = fmaf(fmaxf(accA[nt][r], 0.f), wsum4[nt], sA);
            sB = fmaf(fmaxf(accB[nt][r], 0.f), wsum4[nt], sB);
        }
        sA += __shfl_xor(sA, 1); sA += __shfl_xor(sA, 2);
        sA += __shfl_xor(sA, 4); sA += __shfl_xor(sA, 8);
        sB += __shfl_xor(sB, 1); sB += __shfl_xor(sB, 2);
        sB += __shfl_xor(sB, 4); sB += __shfl_xor(sB, 8);
        if (m == 0) {
            const int nA = node0A + quad * 4 + r;
            const int nB = node0B + quad * 4 + r;
            if (nA < N_NODESC) q[nA] = sA;
            if (nB < N_NODESC) q[nB] = sB;
        }
    }
}

// ---------------------------------------------------------------------------
// edge_kernel: 8 edges/thread, batched phases:
// all edge loads -> all q gathers -> compute -> store wlp/whp ->
// fire-and-forget u64 atomics into per-node degree tables.
// deg entry: (count << 40) | sum of 20-bit fixed-point wlp.
__global__ __launch_bounds__(256) void edge_kernel(
    const int* __restrict__ edges,
    const float* __restrict__ noise,
    const float* __restrict__ b_edge,
    const float* __restrict__ q,
    unsigned long long* __restrict__ degS,
    unsigned long long* __restrict__ degD,
    float* __restrict__ out,
    const int* __restrict__ flag) {
    const int tid = threadIdx.x;
    const int is64 = *flag;
    const float be = b_edge[0];
    const int e0 = blockIdx.x * (256 * EPB) + tid;

    int sA[EPB], dA[EPB];
    #pragma unroll
    for (int i = 0; i < EPB; ++i) {
        const int e = e0 + i * 256;
        sA[i] = -1;
        if (e < N_EDGESC) load_edge(edges, e, is64, sA[i], dA[i]);
    }
    float qs[EPB], qd[EPB];
    #pragma unroll
    for (int i = 0; i < EPB; ++i) {
        if (sA[i] >= 0) { qs[i] = q[sA[i]]; qd[i] = q[dA[i]]; }
    }
    float wlpA[EPB];
    #pragma unroll
    for (int i = 0; i < EPB; ++i) {
        if (sA[i] >= 0) {
            const int e = e0 + i * 256;
            const float raw = 0.5f * (qs[i] + qd[i]) + be;
            const float u = noise[e];
            const float eps = (BIASC - (1.0f - BIASC)) * u + (1.0f - BIASC);
            const float gate = logf(eps) - log1pf(-eps);
            const float wlp = 1.0f / (1.0f + expf(-(gate + raw)));
            wlpA[i] = wlp;
            out[2 * MC + e] = wlp;
            out[2 * MC + N_EDGESC + e] = 1.0f - wlp;
        }
    }
    #pragma unroll
    for (int i = 0; i < EPB; ++i) {
        if (sA[i] >= 0) {
            const unsigned w20 =
                min((unsigned)(wlpA[i] * W20SCALE + 0.5f), 0xFFFFFu);
            const unsigned long long v = CNTONE | (unsigned long long)w20;
            atomicAdd(&degS[sA[i]], v);
            atomicAdd(&degD[dA[i]], v);
        }
    }
}

// ---------------------------------------------------------------------------
// final kernel: 4 elements/thread. Reads edges + wlp, gathers the two u64
// degree entries per edge, computes rsqrt normalization inline.
// Self-loop unified as an edge with s=d=n, wl=1+EOS (first output);
// second output forced 1.0.
__global__ __launch_bounds__(256) void final_kernel(
    const int* __restrict__ edges,
    const unsigned long long* __restrict__ degS,
    const unsigned long long* __restrict__ degD,
    float* __restrict__ out,
    const int* __restrict__ flag) {
    const int tid = threadIdx.x;
    const int i0 = blockIdx.x * 1024 + tid;
    const int is64 = *flag;
    int sA[4], dA[4];
    float wl[4], wh[4];
    #pragma unroll
    for (int j = 0; j < 4; ++j) {
        const int i = i0 + j * 256;
        sA[j] = -1;
        if (i < N_EDGESC) {
            load_edge(edges, i, is64, sA[j], dA[j]);
        } else if (i < MC) {
            sA[j] = dA[j] = i - N_EDGESC;
        }
    }
    #pragma unroll
    for (int j = 0; j < 4; ++j) {
        const int i = i0 + j * 256;
        if (i < N_EDGESC) {
            const float wlp = out[2 * MC + i];
            wl[j] = wlp + EOSC;
            wh[j] = (1.0f - wlp) + EOSC;
        } else {
            wl[j] = 1.0f + EOSC;
        }
    }
    unsigned long long aS[4], aD[4];
    #pragma unroll
    for (int j = 0; j < 4; ++j) {
        if (sA[j] >= 0) { aS[j] = degS[sA[j]]; aD[j] = degD[dA[j]]; }
    }
    #pragma unroll
    for (int j = 0; j < 4; ++j) {
        const int i = i0 + j * 256;
        if (sA[j] >= 0) {
            const float sumS = (float)(aS[j] & SUMMASK) * W20INV;
            const float cS = (float)(aS[j] >> 40);
            const float sumD = (float)(aD[j] & SUMMASK) * W20INV;
            const float cD = (float)(aD[j] >> 40);
            const float rSx = rsqrtf(1.0f + sumS);        // lp out-degree
            const float rDx = rsqrtf(1.0f + sumD);        // lp in-degree
            out[i] = wl[j] * rSx * rDx;
            if (i < N_EDGESC) {
                const float rSy = rsqrtf(1.0f + cS - sumS);  // hp out-degree
                const float rDy = rsqrtf(1.0f + cD - sumD);  // hp in-degree
                out[MC + i] = -ALPHAC * wh[j] * rSy * rDy;
            } else {
                out[MC + i] = 1.0f;
            }
        }
    }
}

// ---------------------------------------------------------------------------
extern "C" void kernel_launch(void* const* d_in, const int* in_sizes, int n_in,
                              void* d_out, int out_size, void* d_ws, size_t ws_size,
                              hipStream_t stream) {
    const float* features = (const float*)d_in[0];
    const int* edges      = (const int*)d_in[1];
    const float* noise    = (const float*)d_in[2];
    const float* W_emb    = (const float*)d_in[3];
    const float* b_emb    = (const float*)d_in[4];
    const float* W_edge   = (const float*)d_in[5];
    const float* b_edge   = (const float*)d_in[6];
    float* out = (float*)d_out;
    char* ws = (char*)d_ws;

    // ws layout (bytes):
    //   [0, 400000)          q    : N f32
    //   [400000, 1200000)    degS : N u64  (count<<40 | sum20)
    //   [1200000, 2000000)   degD : N u64
    //   [2000000, 2000004)   flag
    float* q = (float*)ws;
    unsigned long long* degS = (unsigned long long*)(ws + 400000);
    unsigned long long* degD = (unsigned long long*)(ws + 1200000);
    int* flag = (int*)(ws + 2000000);

    node_kernel<<<782, 256, 0, stream>>>(features, W_emb, b_emb, W_edge, edges,
                                         q, degS, flag);
    edge_kernel<<<(N_EDGESC + 256 * EPB - 1) / (256 * EPB), 256, 0, stream>>>(
        edges, noise, b_edge, q, degS, degD, out, flag);
    final_kernel<<<(MC + 1023) / 1024, 256, 0, stream>>>(edges, degS, degD, out,
                                                         flag);
}

// Round 3
// 260.616 us; speedup vs baseline: 1.4099x; 1.4099x over previous
//
#include <hip/hip_runtime.h>
#include <hip/hip_bf16.h>
#include <math.h>

#define N_NODESC 100000
#define N_EDGESC 1600000
#define IN_DIMC 256
#define HIDC 64
#define ALPHAC 0.1f
#define BIASC 1e-4f
#define EOSC 1e-10f

#define MC (N_EDGESC + N_NODESC)   // 1,700,000
#define NBUCK 400                  // buckets of 256 nodes (shift 8), per side
#define BSHIFT 8
#define BMASK 255
#define BCAP 5120u                 // expected 4096/bucket, +16 sigma
#define W20SCALE 1048576.0f        // 2^20
#define W20INV (1.0f / 1048576.0f)
#define SUMMASK ((1ull << 40) - 1)
#define CNTONE (1ull << 40)
#define EPB 8                      // edges per thread in edge_scatter

typedef __attribute__((ext_vector_type(8))) short short8;
typedef __attribute__((ext_vector_type(4))) float f32x4;

#define WT_STRIDE 264  // bf16 per j-row: 256 + 8 pad (528 B, 16B-aligned)

// edges may arrive as int32 (JAX x64-off) or int64 little-endian.
__device__ inline void load_edge(const int* __restrict__ edges, int e, int is64,
                                 int& src, int& dst) {
    if (is64) {
        const int2 a = ((const int2*)edges)[e];
        const int2 b = ((const int2*)edges)[N_EDGESC + e];
        src = a.x; dst = b.x;
    } else {
        src = edges[e];
        dst = edges[N_EDGESC + e];
    }
}

__device__ inline short pkbf(float x) {
    union { __hip_bfloat16 b; short s; } u;
    u.b = __float2bfloat16(x);
    return u.s;
}

// ---------------------------------------------------------------------------
// node kernel (MFMA): q[n] = relu(feat[n] @ W + b) @ (We[:64]+We[64:])
// 2 node-tiles per wave. Block 0 zeroes the 800 bucket cursors + detects
// int32/int64 edge layout.
__global__ __launch_bounds__(256, 3) void node_kernel(
    const float* __restrict__ features,
    const float* __restrict__ W_emb,
    const float* __restrict__ b_emb,
    const float* __restrict__ W_edge,
    const int* __restrict__ edges,
    float* __restrict__ q,
    unsigned* __restrict__ cursor,
    int* __restrict__ flag) {
    __shared__ __align__(16) short Wt[HIDC * WT_STRIDE];  // ~33.8 KB
    const int tid = threadIdx.x;
    if (blockIdx.x == 0) {
        if (tid == 0) {
            int z = 0;
            #pragma unroll
            for (int i = 0; i < 16; ++i) z |= edges[2 * i + 1];
            *flag = (z == 0) ? 1 : 0;  // 1 => int64 layout
        }
        for (int b = tid; b < 2 * NBUCK; b += 256) cursor[b] = 0u;
    }
    {
        const float4* Wg = (const float4*)W_emb;
        #pragma unroll
        for (int i = 0; i < 16; ++i) {
            const int f4 = tid + 256 * i;
            const float4 g = Wg[f4];
            const int flat = 4 * f4;
            const int k = flat >> 6;
            const int j0 = flat & 63;
            Wt[(j0 + 0) * WT_STRIDE + k] = pkbf(g.x);
            Wt[(j0 + 1) * WT_STRIDE + k] = pkbf(g.y);
            Wt[(j0 + 2) * WT_STRIDE + k] = pkbf(g.z);
            Wt[(j0 + 3) * WT_STRIDE + k] = pkbf(g.w);
        }
    }
    const int lane = tid & 63;
    const int wave = tid >> 6;
    const int quad = lane >> 4;
    const int m = lane & 15;
    f32x4 accA[4], accB[4];
    float wsum4[4];
    #pragma unroll
    for (int nt = 0; nt < 4; ++nt) {
        const int j = m + 16 * nt;
        const float b = b_emb[j];
        accA[nt] = (f32x4){b, b, b, b};
        accB[nt] = (f32x4){b, b, b, b};
        wsum4[nt] = W_edge[j] + W_edge[HIDC + j];
    }
    __syncthreads();

    const int node0A = blockIdx.x * 128 + wave * 16;
    const int node0B = node0A + 64;
    const float* frA = features + (size_t)min(node0A + m, N_NODESC - 1) * IN_DIMC;
    const float* frB = features + (size_t)min(node0B + m, N_NODESC - 1) * IN_DIMC;

    #pragma unroll
    for (int ks = 0; ks < 8; ++ks) {
        const int kk = ks * 32 + quad * 8;
        const float4 fa0 = *(const float4*)(frA + kk);
        const float4 fb0 = *(const float4*)(frA + kk + 4);
        const float4 fa1 = *(const float4*)(frB + kk);
        const float4 fb1 = *(const float4*)(frB + kk + 4);
        short8 afA, afB;
        afA[0] = pkbf(fa0.x); afA[1] = pkbf(fa0.y);
        afA[2] = pkbf(fa0.z); afA[3] = pkbf(fa0.w);
        afA[4] = pkbf(fb0.x); afA[5] = pkbf(fb0.y);
        afA[6] = pkbf(fb0.z); afA[7] = pkbf(fb0.w);
        afB[0] = pkbf(fa1.x); afB[1] = pkbf(fa1.y);
        afB[2] = pkbf(fa1.z); afB[3] = pkbf(fa1.w);
        afB[4] = pkbf(fb1.x); afB[5] = pkbf(fb1.y);
        afB[6] = pkbf(fb1.z); afB[7] = pkbf(fb1.w);
        #pragma unroll
        for (int nt = 0; nt < 4; ++nt) {
            const short8 bf =
                *(const short8*)&Wt[(m + 16 * nt) * WT_STRIDE + kk];
            accA[nt] = __builtin_amdgcn_mfma_f32_16x16x32_bf16(afA, bf, accA[nt],
                                                               0, 0, 0);
            accB[nt] = __builtin_amdgcn_mfma_f32_16x16x32_bf16(afB, bf, accB[nt],
                                                               0, 0, 0);
        }
    }

    #pragma unroll
    for (int r = 0; r < 4; ++r) {
        float sA = 0.f, sB = 0.f;
        #pragma unroll
        for (int nt = 0; nt < 4; ++nt) {
            sA = fmaf(fmaxf(accA[nt][r], 0.f), wsum4[nt], sA);
            sB = fmaf(fmaxf(accB[nt][r], 0.f), wsum4[nt], sB);
        }
        sA += __shfl_xor(sA, 1); sA += __shfl_xor(sA, 2);
        sA += __shfl_xor(sA, 4); sA += __shfl_xor(sA, 8);
        sB += __shfl_xor(sB, 1); sB += __shfl_xor(sB, 2);
        sB += __shfl_xor(sB, 4); sB += __shfl_xor(sB, 8);
        if (m == 0) {
            const int nA = node0A + quad * 4 + r;
            const int nB = node0B + quad * 4 + r;
            if (nA < N_NODESC) q[nA] = sA;
            if (nB < N_NODESC) q[nB] = sB;
        }
    }
}

// ---------------------------------------------------------------------------
// edge_scatter: 8 edges/thread, batched phases:
// all edge loads -> all q gathers -> compute+rank -> claim -> scatter.
// Records: u32 = (node_local_8b << 20) | wlp_fixed_20b, into ws bucket arrays.
__global__ __launch_bounds__(256) void edge_scatter(
    const int* __restrict__ edges,
    const float* __restrict__ noise,
    const float* __restrict__ b_edge,
    const float* __restrict__ q,
    unsigned* __restrict__ cursor,
    unsigned* __restrict__ recS,
    unsigned* __restrict__ recD,
    float* __restrict__ out,
    const int* __restrict__ flag) {
    __shared__ unsigned hist[2][4][NBUCK];   // 12.8 KB
    __shared__ unsigned wbase[2][4][NBUCK];  // 12.8 KB
    const int tid = threadIdx.x;
    const int wave = tid >> 6;
    for (int i = tid; i < 2 * 4 * NBUCK; i += 256)
        ((unsigned*)hist)[i] = 0u;
    __syncthreads();
    const int is64 = *flag;
    const float be = b_edge[0];
    const int e0 = blockIdx.x * (256 * EPB) + tid;

    int sA[EPB], dA[EPB];
    #pragma unroll
    for (int i = 0; i < EPB; ++i) {
        const int e = e0 + i * 256;
        sA[i] = -1;
        if (e < N_EDGESC) load_edge(edges, e, is64, sA[i], dA[i]);
    }
    float qs[EPB], qd[EPB];
    #pragma unroll
    for (int i = 0; i < EPB; ++i) {
        if (sA[i] >= 0) { qs[i] = q[sA[i]]; qd[i] = q[dA[i]]; }
    }
    float wlpA[EPB];
    unsigned rkS[EPB], rkD[EPB];
    #pragma unroll
    for (int i = 0; i < EPB; ++i) {
        if (sA[i] >= 0) {
            const int e = e0 + i * 256;
            const float raw = 0.5f * (qs[i] + qd[i]) + be;
            const float u = noise[e];
            const float eps = (BIASC - (1.0f - BIASC)) * u + (1.0f - BIASC);
            const float gate = logf(eps) - log1pf(-eps);
            const float wlp = 1.0f / (1.0f + expf(-(gate + raw)));
            wlpA[i] = wlp;
            out[2 * MC + e] = wlp;
            out[2 * MC + N_EDGESC + e] = 1.0f - wlp;
            rkS[i] = atomicAdd(&hist[0][wave][sA[i] >> BSHIFT], 1u);
            rkD[i] = atomicAdd(&hist[1][wave][dA[i] >> BSHIFT], 1u);
        }
    }
    __syncthreads();
    // claim phase: each thread claims cursors for buckets tid, tid+256 (S & D)
    for (int b = tid; b < NBUCK; b += 256) {
        const unsigned h0 = hist[0][0][b], h1 = hist[0][1][b];
        const unsigned h2 = hist[0][2][b], h3 = hist[0][3][b];
        const unsigned base = atomicAdd(&cursor[b], h0 + h1 + h2 + h3);
        wbase[0][0][b] = base;
        wbase[0][1][b] = base + h0;
        wbase[0][2][b] = base + h0 + h1;
        wbase[0][3][b] = base + h0 + h1 + h2;
    }
    for (int b = tid; b < NBUCK; b += 256) {
        const unsigned h0 = hist[1][0][b], h1 = hist[1][1][b];
        const unsigned h2 = hist[1][2][b], h3 = hist[1][3][b];
        const unsigned base = atomicAdd(&cursor[NBUCK + b], h0 + h1 + h2 + h3);
        wbase[1][0][b] = base;
        wbase[1][1][b] = base + h0;
        wbase[1][2][b] = base + h0 + h1;
        wbase[1][3][b] = base + h0 + h1 + h2;
    }
    __syncthreads();
    #pragma unroll
    for (int i = 0; i < EPB; ++i) {
        if (sA[i] >= 0) {
            const int s = sA[i], d = dA[i];
            const unsigned w20 =
                min((unsigned)(wlpA[i] * W20SCALE + 0.5f), 0xFFFFFu);
            const unsigned pS = wbase[0][wave][s >> BSHIFT] + rkS[i];
            const unsigned pD = wbase[1][wave][d >> BSHIFT] + rkD[i];
            if (pS < BCAP)
                recS[(unsigned)(s >> BSHIFT) * BCAP + pS] =
                    ((unsigned)(s & BMASK) << 20) | w20;
            if (pD < BCAP)
                recD[(unsigned)(d >> BSHIFT) * BCAP + pD] =
                    ((unsigned)(d & BMASK) << 20) | w20;
        }
    }
}

// ---------------------------------------------------------------------------
// gather_kernel: block owns one bucket (0..399 = src side, 400..799 = dst).
// Records -> LDS u64 table -> decode -> per-node float2 rsqrt pair.
// rS[n] = {r_lp_out, r_hp_out}; rD[n] = {r_lp_in, r_hp_in}.
__global__ __launch_bounds__(256) void gather_kernel(
    const unsigned* __restrict__ recS,
    const unsigned* __restrict__ recD,
    const unsigned* __restrict__ cursor,
    float2* __restrict__ rS,
    float2* __restrict__ rD) {
    __shared__ unsigned long long table[256];
    const int bid = blockIdx.x;
    const int isD = bid >= NBUCK;
    const int bkt = isD ? bid - NBUCK : bid;
    const unsigned* rec = (isD ? recD : recS) + (unsigned)bkt * BCAP;
    const unsigned cnt = min(cursor[isD ? NBUCK + bkt : bkt], BCAP);
    const int tid = threadIdx.x;
    table[tid] = 0ull;
    __syncthreads();
    for (unsigned i = tid; i < cnt; i += 256) {
        const unsigned r = rec[i];
        atomicAdd(&table[r >> 20], CNTONE | (unsigned long long)(r & 0xFFFFFu));
    }
    __syncthreads();
    float2* dstp = isD ? rD : rS;
    const int node = (bkt << BSHIFT) + tid;
    if (node < N_NODESC) {
        const unsigned long long a = table[tid];
        const float sum = (float)(a & SUMMASK) * W20INV;
        const float cf = (float)(a >> 40);
        float2 r;
        r.x = rsqrtf(1.0f + sum);        // lp degree (self-loop = 1)
        r.y = rsqrtf(1.0f + cf - sum);   // hp degree
        dstp[node] = r;
    }
}

// ---------------------------------------------------------------------------
// final kernel: 4 elements/thread, batched phases. Self-loop unified as an
// edge with s=d=n, wlp_eff=1+EOS (first output); second output forced 1.0.
__global__ __launch_bounds__(256) void final_kernel(
    const int* __restrict__ edges,
    const float2* __restrict__ rS,
    const float2* __restrict__ rD,
    float* __restrict__ out,
    const int* __restrict__ flag) {
    const int tid = threadIdx.x;
    const int i0 = blockIdx.x * 1024 + tid;
    const int is64 = *flag;
    int sA[4], dA[4];
    float wl[4], wh[4];
    #pragma unroll
    for (int j = 0; j < 4; ++j) {
        const int i = i0 + j * 256;
        sA[j] = -1;
        if (i < N_EDGESC) {
            load_edge(edges, i, is64, sA[j], dA[j]);
        } else if (i < MC) {
            sA[j] = dA[j] = i - N_EDGESC;
        }
    }
    #pragma unroll
    for (int j = 0; j < 4; ++j) {
        const int i = i0 + j * 256;
        if (i < N_EDGESC) {
            wl[j] = out[2 * MC + i] + EOSC;
            wh[j] = out[2 * MC + N_EDGESC + i] + EOSC;
        } else {
            wl[j] = 1.0f + EOSC;
        }
    }
    float2 a[4], b[4];
    #pragma unroll
    for (int j = 0; j < 4; ++j) {
        if (sA[j] >= 0) { a[j] = rS[sA[j]]; b[j] = rD[dA[j]]; }
    }
    #pragma unroll
    for (int j = 0; j < 4; ++j) {
        const int i = i0 + j * 256;
        if (sA[j] >= 0) {
            out[i] = wl[j] * a[j].x * b[j].x;
            out[MC + i] = (i < N_EDGESC)
                              ? -ALPHAC * wh[j] * a[j].y * b[j].y
                              : 1.0f;
        }
    }
}

// ---------------------------------------------------------------------------
extern "C" void kernel_launch(void* const* d_in, const int* in_sizes, int n_in,
                              void* d_out, int out_size, void* d_ws, size_t ws_size,
                              hipStream_t stream) {
    const float* features = (const float*)d_in[0];
    const int* edges      = (const int*)d_in[1];
    const float* noise    = (const float*)d_in[2];
    const float* W_emb    = (const float*)d_in[3];
    const float* b_emb    = (const float*)d_in[4];
    const float* W_edge   = (const float*)d_in[5];
    const float* b_edge   = (const float*)d_in[6];
    float* out = (float*)d_out;
    char* ws = (char*)d_ws;

    // ws layout (bytes):
    //   [0, 400000)            q  : N f32
    //   [400000, 1200000)      rS : N float2
    //   [1200000, 2000000)     rD : N float2
    //   [2000000, 2000004)     flag
    //   [2000064, 2003264)     cursor : 2*400 u32
    //   [2097152, 10289152)    recS : 400*5120 u32
    //   [10289152, 18481152)   recD : 400*5120 u32
    float* q = (float*)ws;
    float2* rS = (float2*)(ws + 400000);
    float2* rD = (float2*)(ws + 1200000);
    int* flag = (int*)(ws + 2000000);
    unsigned* cursor = (unsigned*)(ws + 2000064);
    unsigned* recS = (unsigned*)(ws + 2097152);
    unsigned* recD = (unsigned*)(ws + 10289152);

    node_kernel<<<782, 256, 0, stream>>>(features, W_emb, b_emb, W_edge, edges,
                                         q, cursor, flag);
    edge_scatter<<<(N_EDGESC + 256 * EPB - 1) / (256 * EPB), 256, 0, stream>>>(
        edges, noise, b_edge, q, cursor, recS, recD, out, flag);
    gather_kernel<<<2 * NBUCK, 256, 0, stream>>>(recS, recD, cursor, rS, rD);
    final_kernel<<<(MC + 1023) / 1024, 256, 0, stream>>>(edges, rS, rD, out, flag);
}